// Round 4
// baseline (350.918 us; speedup 1.0000x reference)
//
#include <hip/hip_runtime.h>
#include <hip/hip_fp16.h>
#include <math.h>

namespace {
constexpr int kH = 384, kW = 384, kBn = 2;
constexpr int kHW = kH * kW;       // 147456
constexpr int kOMD = 112;
constexpr int kNB = kBn * (kHW / 64);   // 4608 blocks
constexpr int kNB8 = kNB / 8;           // 576 per XCD
}

typedef _Float16 half8 __attribute__((ext_vector_type(8)));
typedef float f32x4 __attribute__((ext_vector_type(4)));

// MFMA A-fragment-ordered weight tables (packed once by k_value block 0).
// g_WomF[jt(8)][kh(2)][lane(64)][8]: A=Wom^T, row(slot)=jt*16+(l&15), k=kh*32+(l>>4)*8+jj
//   slot = g*32 + j (j<27 valid, else 0)  -> j-tiles are slot-contiguous.
// g_WoF [mt(4)][kh(2)][lane(64)][8]: A=Wo^T,  row(co)=mt*16+(l&15),  k same map.
__device__ __align__(16) _Float16 g_WomF[8 * 2 * 64 * 8];
__device__ __align__(16) _Float16 g_WoF[4 * 2 * 64 * 8];

__device__ __forceinline__ int swz(int t) {
    // XCD-aware: round-robin dispatch -> each XCD gets a contiguous range
    return (t & 7) * kNB8 + (t >> 3);
}

__device__ __forceinline__ unsigned pack2h(float a, float b) {
    unsigned short lo = __builtin_bit_cast(unsigned short, __float2half_rn(a));
    unsigned short hi = __builtin_bit_cast(unsigned short, __float2half_rn(b));
    return (unsigned)lo | ((unsigned)hi << 16);
}

__device__ __forceinline__ float h2f_lo(unsigned u) {
    __half2 h = __builtin_bit_cast(__half2, u);
    return __half2float(h.x);
}
__device__ __forceinline__ float h2f_hi(unsigned u) {
    __half2 h = __builtin_bit_cast(__half2, u);
    return __half2float(h.y);
}

// fp16 pair fma: acc += wgt * half2(u)  -> compiler forms v_fma_mix_f32
__device__ __forceinline__ void fma2h(float& a0, float& a1, float w, unsigned u) {
    __half2 h = __builtin_bit_cast(__half2, u);
    a0 = fmaf(w, __half2float(h.x), a0);
    a1 = fmaf(w, __half2float(h.y), a1);
}

__device__ __forceinline__ half8 ld_frag_g(const _Float16* ptr) {
    return __builtin_bit_cast(half8, *(const uint4*)ptr);
}

// K1: value[b][g][yx][c16] (fp16) = inp(b,:,yx) @ Wv + bv   (unchanged from r3)
// Block 0 additionally packs Wom/Wo into MFMA-fragment-ordered fp16 tables.
__global__ __launch_bounds__(256) void k_value(
        const float* __restrict__ inp, const float* __restrict__ Wv,
        const float* __restrict__ bv, const float* __restrict__ Wom,
        const float* __restrict__ Wo, unsigned short* __restrict__ value) {
    __shared__ float xin[64][64];
    const int tid = threadIdx.x;

    if (blockIdx.x == 0) {          // one-time fragment-order weight prep
        for (int i = tid; i < 8 * 2 * 64 * 8; i += 256) {
            const int jj = i & 7, l = (i >> 3) & 63, kh = (i >> 9) & 1, jt = i >> 10;
            const int slot = jt * 16 + (l & 15);
            const int g = slot >> 5, j = slot & 31;
            const int ch = kh * 32 + ((l >> 4) & 3) * 8 + jj;
            const float v = (j < 27) ? Wom[ch * kOMD + g * 27 + j] : 0.f;
            g_WomF[i] = (_Float16)v;
        }
        for (int i = tid; i < 4 * 2 * 64 * 8; i += 256) {
            const int jj = i & 7, l = (i >> 3) & 63, kh = (i >> 9) & 1, mt = i >> 10;
            const int co = mt * 16 + (l & 15);
            const int ch = kh * 32 + ((l >> 4) & 3) * 8 + jj;
            g_WoF[i] = (_Float16)Wo[ch * 64 + co];
        }
    }

    const int bid = swz(blockIdx.x);
    const int b = bid / (kHW / 64);
    const int pix0 = (bid % (kHW / 64)) * 64;
    const float* ib = inp + (size_t)b * 64 * kHW + pix0;
    for (int i = tid; i < 1024; i += 256) {
        const int c = i >> 4, p4 = (i & 15) << 2;
        const float4 v = *(const float4*)(ib + (size_t)c * kHW + p4);
        *(float4*)&xin[c][p4] = v;
    }
    __syncthreads();

    const int p = tid & 63;
    const int gs = __builtin_amdgcn_readfirstlane(tid >> 6);  // wave-uniform

    float acc[16];
    {
        const float* bg = bv + gs * 16;            // wave-uniform -> s_load
        #pragma unroll
        for (int j = 0; j < 16; ++j) acc[j] = bg[j];
    }
    #pragma unroll 4
    for (int ci = 0; ci < 64; ++ci) {
        const float a = xin[ci][p];                // 1 ds_read_b32 / ci
        const float* wr = Wv + ci * 64 + gs * 16;  // wave-uniform -> s_load
        #pragma unroll
        for (int j = 0; j < 16; ++j) acc[j] = fmaf(a, wr[j], acc[j]);
    }

    unsigned u[8];
    #pragma unroll
    for (int j = 0; j < 8; ++j) u[j] = pack2h(acc[2 * j], acc[2 * j + 1]);
    uint4* vo = (uint4*)(value + ((size_t)(b * 4 + gs) * kHW + pix0 + p) * 16);
    vo[0] = make_uint4(u[0], u[1], u[2], u[3]);
    vo[1] = make_uint4(u[4], u[5], u[6], u[7]);
}

// K2: dw conv -> om matvec (MFMA) -> deformable sampling -> @Wo (MFMA)
// One block = 64 consecutive pixels of one row. 256 threads = 4 waves.
__global__ __launch_bounds__(256) void k_main(
        const float* __restrict__ inp, const float* __restrict__ Wdw,
        const float* __restrict__ bdw, const float* __restrict__ bom,
        const unsigned short* __restrict__ value, float* __restrict__ out) {
    // blocked fp16 activations: bact[ch8][px][8ch] -> conflict-light MFMA B-frag reads
    __shared__ unsigned bact[8][64][4];      // 8 KB; dw (A->B), then sampled (C->D)
    __shared__ unsigned short omlh[64][136]; // 17 KB; om matvec result [px][slot]

    const int tid = threadIdx.x;
    const int bid = swz(blockIdx.x);
    const int b = bid / (kH * (kW / 64));
    const int rem = bid % (kH * (kW / 64));
    const int h = rem / (kW / 64);
    const int w0 = (rem % (kW / 64)) * 64;

    const int p = tid & 63;
    const int q = p >> 4, lr = p & 15;                           // quarter, in-quarter
    const int gs = __builtin_amdgcn_readfirstlane(tid >> 6);     // wave id -> SGPR

    // ---- stage A: depthwise 3x3 conv (zero pad) -> fp16 blocked LDS ----
    {
        const int w = w0 + p;
        float sv[16];
        #pragma unroll 4
        for (int cc = 0; cc < 16; ++cc) {
            const int c = gs * 16 + cc;                 // wave-uniform
            const float* ib = inp + (size_t)(b * 64 + c) * kHW;
            float s = bdw[c];
            #pragma unroll
            for (int r = 0; r < 3; ++r) {
                const int y = h - 1 + r;
                if (y >= 0 && y < kH) {
                    const float* rowp = ib + (size_t)y * kW;
                    #pragma unroll
                    for (int kx = 0; kx < 3; ++kx) {
                        const int x = w - 1 + kx;
                        const float v = (x >= 0 && x < kW) ? rowp[x] : 0.f;
                        s = fmaf(v, Wdw[c * 9 + r * 3 + kx], s);
                    }
                }
            }
            sv[cc] = s;
        }
        unsigned u[8];
        #pragma unroll
        for (int j = 0; j < 8; ++j) u[j] = pack2h(sv[2 * j], sv[2 * j + 1]);
        *(uint4*)&bact[2 * gs][p][0]     = make_uint4(u[0], u[1], u[2], u[3]);
        *(uint4*)&bact[2 * gs + 1][p][0] = make_uint4(u[4], u[5], u[6], u[7]);
    }
    __syncthreads();

    // ---- stage B: om = dw @ Wom via MFMA; wave gs owns px-tile gs ----
    {
        half8 bfr[2];
        #pragma unroll
        for (int kh = 0; kh < 2; ++kh)
            bfr[kh] = __builtin_bit_cast(half8,
                    *(const uint4*)&bact[kh * 4 + q][gs * 16 + lr][0]);
        const int px = gs * 16 + lr;
        #pragma unroll
        for (int jt = 0; jt < 8; ++jt) {
            const half8 a0 = ld_frag_g(g_WomF + ((jt * 2 + 0) * 64 + p) * 8);
            const half8 a1 = ld_frag_g(g_WomF + ((jt * 2 + 1) * 64 + p) * 8);
            f32x4 acc = {0.f, 0.f, 0.f, 0.f};
            acc = __builtin_amdgcn_mfma_f32_16x16x32_f16(a0, bfr[0], acc, 0, 0, 0);
            acc = __builtin_amdgcn_mfma_f32_16x16x32_f16(a1, bfr[1], acc, 0, 0, 0);
            uint2 st;
            st.x = pack2h(acc[0], acc[1]);
            st.y = pack2h(acc[2], acc[3]);
            *(uint2*)&omlh[px][jt * 16 + q * 4] = st;   // 4 consecutive slots
        }
    }
    __syncthreads();   // omlh ready; bact B-frag reads done (stage C overwrites)

    // ---- stage C: deformable bilinear sampling (fp16 value, v_fma_mix) ----
    {
        float om[27];
        {
            const unsigned short* orow = &omlh[p][gs * 32];   // 16B-aligned
            const uint4 r0 = *(const uint4*)(orow);
            const uint4 r1 = *(const uint4*)(orow + 8);
            const uint4 r2 = *(const uint4*)(orow + 16);
            const uint2 r3 = *(const uint2*)(orow + 24);
            const unsigned rr[14] = {r0.x, r0.y, r0.z, r0.w, r1.x, r1.y, r1.z, r1.w,
                                     r2.x, r2.y, r2.z, r2.w, r3.x, r3.y};
            const float* bg = bom + gs * 27;                  // wave-uniform s_load
            #pragma unroll
            for (int j = 0; j < 27; ++j) {
                const float v = (j & 1) ? h2f_hi(rr[j >> 1]) : h2f_lo(rr[j >> 1]);
                om[j] = bg[j] + v;
            }
        }

        float acc[16];
        #pragma unroll
        for (int j = 0; j < 16; ++j) acc[j] = 0.f;
        const float fw = (float)(w0 + p);
        const float fh = (float)h;
        const unsigned short* vbase = value + (size_t)(b * 4 + gs) * kHW * 16;
        #pragma unroll
        for (int k = 0; k < 9; ++k) {
            const int ky = k / 3, kx = k % 3;
            const float dx = om[2 * k];
            const float dy = om[2 * k + 1];
            const float m = om[18 + k];
            const float px = fw + (float)(kx - 1) + dx;
            const float py = fh + (float)(ky - 1) + dy;
            const float x0f = floorf(px), y0f = floorf(py);
            const int x0 = (int)x0f, y0 = (int)y0f;
            const float wx1 = px - x0f, wy1 = py - y0f;
            const float wx0 = 1.f - wx1, wy0 = 1.f - wy1;
            #pragma unroll
            for (int cor = 0; cor < 4; ++cor) {
                const int dy2 = cor >> 1, dx2 = cor & 1;
                const int xi = x0 + dx2, yi = y0 + dy2;
                float wgt = (dy2 ? wy1 : wy0) * (dx2 ? wx1 : wx0) * m;
                if (xi < 0 || xi >= kW || yi < 0 || yi >= kH) wgt = 0.f;
                const int xc = min(max(xi, 0), kW - 1);
                const int yc = min(max(yi, 0), kH - 1);
                const uint4* vp = (const uint4*)(vbase +
                        ((size_t)yc * kW + xc) * 16);
                const uint4 u0 = vp[0];
                const uint4 u1 = vp[1];
                fma2h(acc[0],  acc[1],  wgt, u0.x);
                fma2h(acc[2],  acc[3],  wgt, u0.y);
                fma2h(acc[4],  acc[5],  wgt, u0.z);
                fma2h(acc[6],  acc[7],  wgt, u0.w);
                fma2h(acc[8],  acc[9],  wgt, u1.x);
                fma2h(acc[10], acc[11], wgt, u1.y);
                fma2h(acc[12], acc[13], wgt, u1.z);
                fma2h(acc[14], acc[15], wgt, u1.w);
            }
        }
        // write sampled result in blocked fp16 layout (dw is dead now)
        unsigned u[8];
        #pragma unroll
        for (int j = 0; j < 8; ++j) u[j] = pack2h(acc[2 * j], acc[2 * j + 1]);
        *(uint4*)&bact[2 * gs][p][0]     = make_uint4(u[0], u[1], u[2], u[3]);
        *(uint4*)&bact[2 * gs + 1][p][0] = make_uint4(u[4], u[5], u[6], u[7]);
    }
    __syncthreads();

    // ---- stage D: out = sampled @ Wo via MFMA; coalesced (B,C,H,W) stores ----
    {
        half8 sfr[2];
        #pragma unroll
        for (int kh = 0; kh < 2; ++kh)
            sfr[kh] = __builtin_bit_cast(half8,
                    *(const uint4*)&bact[kh * 4 + q][gs * 16 + lr][0]);
        const int px = gs * 16 + lr;
        #pragma unroll
        for (int mt = 0; mt < 4; ++mt) {
            const half8 a0 = ld_frag_g(g_WoF + ((mt * 2 + 0) * 64 + p) * 8);
            const half8 a1 = ld_frag_g(g_WoF + ((mt * 2 + 1) * 64 + p) * 8);
            f32x4 acc = {0.f, 0.f, 0.f, 0.f};
            acc = __builtin_amdgcn_mfma_f32_16x16x32_f16(a0, sfr[0], acc, 0, 0, 0);
            acc = __builtin_amdgcn_mfma_f32_16x16x32_f16(a1, sfr[1], acc, 0, 0, 0);
            float* ob = out + (size_t)(b * 64 + mt * 16 + q * 4) * kHW
                            + (size_t)h * kW + w0 + px;
            ob[0]            = acc[0];
            ob[kHW]          = acc[1];
            ob[2 * (size_t)kHW] = acc[2];
            ob[3 * (size_t)kHW] = acc[3];
        }
    }
}

extern "C" void kernel_launch(void* const* d_in, const int* in_sizes, int n_in,
                              void* d_out, int out_size, void* d_ws, size_t ws_size,
                              hipStream_t stream) {
    const float* inp = (const float*)d_in[0];
    const float* Wv  = (const float*)d_in[1];
    const float* bv  = (const float*)d_in[2];
    const float* Wdw = (const float*)d_in[3];
    const float* bdw = (const float*)d_in[4];
    const float* Wom = (const float*)d_in[5];
    const float* bom = (const float*)d_in[6];
    const float* Wo  = (const float*)d_in[7];
    float* outp = (float*)d_out;
    unsigned short* value = (unsigned short*)d_ws;   // [b][g][yx][16] fp16 = 37.7 MB

    k_value<<<kNB, 256, 0, stream>>>(inp, Wv, bv, Wom, Wo, value);
    k_main<<<kNB, 256, 0, stream>>>(inp, Wdw, bdw, bom, value, outp);
}

// Round 5
// 306.344 us; speedup vs baseline: 1.1455x; 1.1455x over previous
//
#include <hip/hip_runtime.h>
#include <hip/hip_fp16.h>
#include <math.h>

namespace {
constexpr int kH = 384, kW = 384, kBn = 2;
constexpr int kHW = kH * kW;       // 147456
constexpr int kOMD = 112;
constexpr int kNB = kBn * (kHW / 64);   // 4608 blocks
constexpr int kNB8 = kNB / 8;           // 576 per XCD
}

typedef _Float16 h2 __attribute__((ext_vector_type(2)));

// half2-packed channel-pair weights, prepped once by k_value block 0
__device__ unsigned g_Wom2[32 * kOMD];   // [ci2][j] = (Wom[2ci2][j], Wom[2ci2+1][j])
__device__ unsigned g_Wo2[32 * 64];      // [ci2][co] = (Wo[2ci2][co], Wo[2ci2+1][co])

__device__ __forceinline__ int swz(int t) {
    // XCD-aware: round-robin dispatch -> each XCD gets a contiguous range
    return (t & 7) * kNB8 + (t >> 3);
}

__device__ __forceinline__ unsigned pack2h(float a, float b) {
    unsigned short lo = __builtin_bit_cast(unsigned short, __float2half_rn(a));
    unsigned short hi = __builtin_bit_cast(unsigned short, __float2half_rn(b));
    return (unsigned)lo | ((unsigned)hi << 16);
}

#if __has_builtin(__builtin_amdgcn_fdot2)
__device__ __forceinline__ float dot2(unsigned a, unsigned b, float c) {
    return __builtin_amdgcn_fdot2(__builtin_bit_cast(h2, a),
                                  __builtin_bit_cast(h2, b), c, false);
}
#else
__device__ __forceinline__ float dot2(unsigned a, unsigned b, float c) {
    h2 ha = __builtin_bit_cast(h2, a), hb = __builtin_bit_cast(h2, b);
    c = fmaf((float)ha.x, (float)hb.x, c);
    c = fmaf((float)ha.y, (float)hb.y, c);
    return c;
}
#endif

// accumulate one 16-channel corner (32B) with packed fp16 FMAs (v_pk_fma_f16)
__device__ __forceinline__ void acc8h(__half2* pa, const unsigned short* src,
                                      float wgt) {
    const uint4 u0 = ((const uint4*)src)[0];
    const uint4 u1 = ((const uint4*)src)[1];
    const __half2 w2 = __half2half2(__float2half_rn(wgt));
    pa[0] = __hfma2(w2, __builtin_bit_cast(__half2, u0.x), pa[0]);
    pa[1] = __hfma2(w2, __builtin_bit_cast(__half2, u0.y), pa[1]);
    pa[2] = __hfma2(w2, __builtin_bit_cast(__half2, u0.z), pa[2]);
    pa[3] = __hfma2(w2, __builtin_bit_cast(__half2, u0.w), pa[3]);
    pa[4] = __hfma2(w2, __builtin_bit_cast(__half2, u1.x), pa[4]);
    pa[5] = __hfma2(w2, __builtin_bit_cast(__half2, u1.y), pa[5]);
    pa[6] = __hfma2(w2, __builtin_bit_cast(__half2, u1.z), pa[6]);
    pa[7] = __hfma2(w2, __builtin_bit_cast(__half2, u1.w), pa[7]);
}

// K1: value[b][g][yx][c16] (fp16) = inp(b,:,yx) @ Wv + bv   (unchanged from r3)
// Block 0 additionally packs Wom/Wo into half2-pair device globals.
__global__ __launch_bounds__(256) void k_value(
        const float* __restrict__ inp, const float* __restrict__ Wv,
        const float* __restrict__ bv, const float* __restrict__ Wom,
        const float* __restrict__ Wo, unsigned short* __restrict__ value) {
    __shared__ float xin[64][64];   // [ci][p]; 2-way bank alias = free
    const int tid = threadIdx.x;

    if (blockIdx.x == 0) {          // one-time weight prep (idempotent)
        for (int i = tid; i < 32 * kOMD; i += 256) {
            const int ci2 = i / kOMD, j = i % kOMD;
            g_Wom2[i] = pack2h(Wom[(2 * ci2) * kOMD + j],
                               Wom[(2 * ci2 + 1) * kOMD + j]);
        }
        for (int i = tid; i < 32 * 64; i += 256) {
            const int ci2 = i >> 6, j = i & 63;
            g_Wo2[i] = pack2h(Wo[(2 * ci2) * 64 + j],
                              Wo[(2 * ci2 + 1) * 64 + j]);
        }
    }

    const int bid = swz(blockIdx.x);
    const int b = bid / (kHW / 64);
    const int pix0 = (bid % (kHW / 64)) * 64;
    const float* ib = inp + (size_t)b * 64 * kHW + pix0;
    for (int i = tid; i < 1024; i += 256) {
        const int c = i >> 4, p4 = (i & 15) << 2;
        const float4 v = *(const float4*)(ib + (size_t)c * kHW + p4);
        *(float4*)&xin[c][p4] = v;
    }
    __syncthreads();

    const int p = tid & 63;
    const int gs = __builtin_amdgcn_readfirstlane(tid >> 6);  // wave-uniform

    float acc[16];
    {
        const float* bg = bv + gs * 16;            // wave-uniform -> s_load
        #pragma unroll
        for (int j = 0; j < 16; ++j) acc[j] = bg[j];
    }
    #pragma unroll 4
    for (int ci = 0; ci < 64; ++ci) {
        const float a = xin[ci][p];                // 1 ds_read_b32 / ci
        const float* wr = Wv + ci * 64 + gs * 16;  // wave-uniform -> s_load
        #pragma unroll
        for (int j = 0; j < 16; ++j) acc[j] = fmaf(a, wr[j], acc[j]);
    }

    unsigned u[8];
    #pragma unroll
    for (int j = 0; j < 8; ++j) u[j] = pack2h(acc[2 * j], acc[2 * j + 1]);
    uint4* vo = (uint4*)(value + ((size_t)(b * 4 + gs) * kHW + pix0 + p) * 16);
    vo[0] = make_uint4(u[0], u[1], u[2], u[3]);
    vo[1] = make_uint4(u[4], u[5], u[6], u[7]);
}

// K2: fused depthwise conv -> om matvec (fdot2) -> deformable sampling -> @Wo (fdot2)
// One block = 64 consecutive pixels of one row. 256 threads.
__global__ __launch_bounds__(256) void k_main(
        const float* __restrict__ inp, const float* __restrict__ Wdw,
        const float* __restrict__ bdw, const float* __restrict__ bom,
        const unsigned short* __restrict__ value, float* __restrict__ out) {
    __shared__ unsigned lds2[32][64];   // half2 channel-pairs [ci2][p]; A->B then C->D

    const int tid = threadIdx.x;
    const int bid = swz(blockIdx.x);
    const int b = bid / (kH * (kW / 64));
    const int rem = bid % (kH * (kW / 64));
    const int h = rem / (kW / 64);
    const int w0 = (rem % (kW / 64)) * 64;

    const int p = tid & 63;
    const int gs = __builtin_amdgcn_readfirstlane(tid >> 6);   // wave-uniform -> SGPR

    // ---- stage A: depthwise 3x3 conv (zero pad) -> half2 pairs in lds2 ----
    {
        const int w = w0 + p;
        #pragma unroll 2
        for (int q = 0; q < 8; ++q) {
            float sv[2];
            #pragma unroll
            for (int e = 0; e < 2; ++e) {
                const int c = gs * 16 + 2 * q + e;          // wave-uniform
                const float* ib = inp + (size_t)(b * 64 + c) * kHW;
                float s = bdw[c];
                #pragma unroll
                for (int r = 0; r < 3; ++r) {
                    const int y = h - 1 + r;
                    if (y >= 0 && y < kH) {
                        const float* rowp = ib + (size_t)y * kW;
                        #pragma unroll
                        for (int kx = 0; kx < 3; ++kx) {
                            const int x = w - 1 + kx;
                            const float v = (x >= 0 && x < kW) ? rowp[x] : 0.f;
                            s = fmaf(v, Wdw[c * 9 + r * 3 + kx], s);
                        }
                    }
                }
                sv[e] = s;
            }
            lds2[gs * 8 + q][p] = pack2h(sv[0], sv[1]);
        }
    }
    __syncthreads();

    // ---- stage B: om[27] via v_dot2_f32_f16 (channel pairs), fp32 accum ----
    float om[27];
    {
        const float* bg = bom + gs * 27;                // scalar loads
        #pragma unroll
        for (int j = 0; j < 27; ++j) om[j] = bg[j];
        #pragma unroll 4
        for (int ci2 = 0; ci2 < 32; ++ci2) {
            const unsigned a2 = lds2[ci2][p];           // 1 ds_read_b32 / pair
            const unsigned* wr = g_Wom2 + ci2 * kOMD + gs * 27;  // wave-uniform
            #pragma unroll
            for (int j = 0; j < 27; ++j) om[j] = dot2(a2, wr[j], om[j]);
        }
    }
    __syncthreads();   // lds2 reads done; stage C will overwrite

    // ---- stage C: deformable bilinear sampling (fp16 value, packed fp16 accum) ----
    {
        __half2 pa[8];
        #pragma unroll
        for (int j = 0; j < 8; ++j) pa[j] = __builtin_bit_cast(__half2, 0u);
        const float fw = (float)(w0 + p);
        const float fh = (float)h;
        const unsigned short* vbase = value + (size_t)(b * 4 + gs) * kHW * 16;
        #pragma unroll
        for (int k = 0; k < 9; ++k) {
            const int ky = k / 3, kx = k % 3;
            const float dx = om[2 * k];
            const float dy = om[2 * k + 1];
            const float m = om[18 + k];
            const float px = fw + (float)(kx - 1) + dx;
            const float py = fh + (float)(ky - 1) + dy;
            const float x0f = floorf(px), y0f = floorf(py);
            const int x0 = (int)x0f, y0 = (int)y0f;
            const float wx1 = px - x0f, wy1 = py - y0f;
            const float wx0 = 1.f - wx1, wy0 = 1.f - wy1;
            const bool interior = (x0 >= 0) & (y0 >= 0) &
                                  (x0 < kW - 1) & (y0 < kH - 1);
            if (__all(interior)) {
                // wave-uniform fast path: one base addr, no clamps, no masks
                const unsigned short* b00 = vbase + ((size_t)y0 * kW + x0) * 16;
                const float wy0m = wy0 * m, wy1m = wy1 * m;
                acc8h(pa, b00,                wx0 * wy0m);
                acc8h(pa, b00 + 16,           wx1 * wy0m);
                acc8h(pa, b00 + kW * 16,      wx0 * wy1m);
                acc8h(pa, b00 + kW * 16 + 16, wx1 * wy1m);
            } else {
                #pragma unroll
                for (int cor = 0; cor < 4; ++cor) {
                    const int dy2 = cor >> 1, dx2 = cor & 1;
                    const int xi = x0 + dx2, yi = y0 + dy2;
                    float wgt = (dy2 ? wy1 : wy0) * (dx2 ? wx1 : wx0) * m;
                    if (xi < 0 || xi >= kW || yi < 0 || yi >= kH) wgt = 0.f;
                    const int xc = min(max(xi, 0), kW - 1);
                    const int yc = min(max(yi, 0), kH - 1);
                    acc8h(pa, vbase + ((size_t)yc * kW + xc) * 16, wgt);
                }
            }
        }
        // sampled pairs already packed -> straight to LDS (dw is dead now)
        #pragma unroll
        for (int j = 0; j < 8; ++j)
            lds2[gs * 8 + j][p] = __builtin_bit_cast(unsigned, pa[j]);
    }
    __syncthreads();

    // ---- stage D: final @Wo via v_dot2_f32_f16, coalesced (B,C,H,W) writeout ----
    {
        float acc[16];
        #pragma unroll
        for (int j = 0; j < 16; ++j) acc[j] = 0.f;
        #pragma unroll 4
        for (int ci2 = 0; ci2 < 32; ++ci2) {
            const unsigned a2 = lds2[ci2][p];
            const unsigned* wr = g_Wo2 + ci2 * 64 + gs * 16;   // wave-uniform
            #pragma unroll
            for (int j = 0; j < 16; ++j) acc[j] = dot2(a2, wr[j], acc[j]);
        }
        float* ob = out + (size_t)(b * 64 + gs * 16) * kHW + (size_t)h * kW + w0 + p;
        #pragma unroll
        for (int j = 0; j < 16; ++j) ob[(size_t)j * kHW] = acc[j];
    }
}

extern "C" void kernel_launch(void* const* d_in, const int* in_sizes, int n_in,
                              void* d_out, int out_size, void* d_ws, size_t ws_size,
                              hipStream_t stream) {
    const float* inp = (const float*)d_in[0];
    const float* Wv  = (const float*)d_in[1];
    const float* bv  = (const float*)d_in[2];
    const float* Wdw = (const float*)d_in[3];
    const float* bdw = (const float*)d_in[4];
    const float* Wom = (const float*)d_in[5];
    const float* bom = (const float*)d_in[6];
    const float* Wo  = (const float*)d_in[7];
    float* outp = (float*)d_out;
    unsigned short* value = (unsigned short*)d_ws;   // [b][g][yx][16] fp16 = 37.7 MB

    k_value<<<kNB, 256, 0, stream>>>(inp, Wv, bv, Wom, Wo, value);
    k_main<<<kNB, 256, 0, stream>>>(inp, Wdw, bdw, bom, value, outp);
}